// Round 1
// baseline (2598.025 us; speedup 1.0000x reference)
//
#include <hip/hip_runtime.h>
#include <math.h>

// Problem constants (EarthAttention3D)
#define B_   96
#define NW   10
#define NN   144   // N = 2*6*12
#define CC   192   // C
#define HH   6     // heads
#define DH   32    // head dim
#define QP   33    // q/k/v LDS pitch (conflict-free for stride-1-in-row, stride-QP-in-col)
#define SP   148   // score LDS pitch (multiple of 4 for float4 PV reads)
#define SCALE 0.17677669529663687f  // 1/sqrt(32)

// ---------------------------------------------------------------------------
// Kernel 1: expand bias_table[pos_idx] -> biasNN[w][h][n][m]
// ---------------------------------------------------------------------------
__global__ __launch_bounds__(256) void bias_expand_kernel(
    const float* __restrict__ bias_table, const int* __restrict__ pos,
    float* __restrict__ biasNN)
{
    int i = blockIdx.x * 256 + threadIdx.x;
    const int TOT = NW * HH * NN * NN;
    if (i >= TOT) return;
    int m = i % NN;
    int n = (i / NN) % NN;
    int h = (i / (NN * NN)) % HH;
    int w = i / (NN * NN * HH);
    int idx = pos[n * NN + m];
    biasNN[i] = bias_table[(idx * NW + w) * HH + h];
}

// ---------------------------------------------------------------------------
// Kernel 2: fused per-(b,w,h) QKV + attention. One block per head instance.
//   - stage x[b,w] rows in LDS (2 chunks of 72 rows, reusing score buffer)
//   - q,k,v [144x32] computed into LDS (pitch 33)
//   - 9x9 register-tiled QK^T + bias + mask -> Ss
//   - row softmax in LDS
//   - register-blocked PV -> attn_out[b,w,n, h*32+d]  (layout [B,nW,N,C])
// LDS: 3*144*33*4 + 144*148*4 = 57,024 + 85,248 = 142,272 B (1 block/CU)
// ---------------------------------------------------------------------------
__global__ __launch_bounds__(256) void attn_kernel(
    const float* __restrict__ x, const float* __restrict__ mask,
    const float* __restrict__ w_qkv, const float* __restrict__ b_qkv,
    const float* __restrict__ biasNN, float* __restrict__ attn_out)
{
    __shared__ float qs[NN * QP];
    __shared__ float ks[NN * QP];
    __shared__ float vs[NN * QP];
    __shared__ float Ss[NN * SP];   // also x-staging scratch (needs 72*192 <= 144*148)

    const int bid = blockIdx.x;
    const int h = bid % HH;
    const int w = (bid / HH) % NW;
    const int b = bid / (HH * NW);
    const int tid = threadIdx.x;

    const float* xp = x + (size_t)(b * NW + w) * NN * CC;

    const int d = tid & 31;   // head-dim lane
    const int g = tid >> 5;   // 8 row-groups

    // ---------------- Phase A: QKV (2 chunks of 72 rows) ----------------
    for (int chunk = 0; chunk < 2; chunk++) {
        const int row0 = chunk * 72;
        for (int i = tid; i < 72 * CC; i += 256)
            Ss[i] = xp[(size_t)row0 * CC + i];
        __syncthreads();

        for (int s = 0; s < 3; s++) {
            const int col = s * CC + h * DH + d;     // column in w_qkv [192 x 576]
            float acc[9];
            const float bq = b_qkv[col];
            #pragma unroll
            for (int i = 0; i < 9; i++) acc[i] = bq;

            for (int k0 = 0; k0 < CC; k0 += 16) {
                float wr[16];
                #pragma unroll
                for (int kk = 0; kk < 16; kk++)
                    wr[kk] = w_qkv[(k0 + kk) * 3 * CC + col];
                #pragma unroll
                for (int i = 0; i < 9; i++) {
                    const float* xr = &Ss[(g * 9 + i) * CC + k0];
                    #pragma unroll
                    for (int kk = 0; kk < 16; kk++)
                        acc[i] = fmaf(xr[kk], wr[kk], acc[i]);
                }
            }
            float* dst = (s == 0) ? qs : (s == 1) ? ks : vs;
            #pragma unroll
            for (int i = 0; i < 9; i++)
                dst[(row0 + g * 9 + i) * QP + d] = acc[i];
        }
        __syncthreads();
    }

    // ---------------- Phase B: scores, 16x16 thread-tiles of 9x9 ----------------
    {
        const int ti = tid >> 4, tj = tid & 15;
        const int n0 = ti * 9, m0 = tj * 9;
        float acc[9][9];
        #pragma unroll
        for (int i = 0; i < 9; i++)
            #pragma unroll
            for (int j = 0; j < 9; j++) acc[i][j] = 0.f;

        for (int dd = 0; dd < DH; dd++) {
            float qr[9], kr[9];
            #pragma unroll
            for (int i = 0; i < 9; i++) qr[i] = qs[(n0 + i) * QP + dd];
            #pragma unroll
            for (int j = 0; j < 9; j++) kr[j] = ks[(m0 + j) * QP + dd];
            #pragma unroll
            for (int i = 0; i < 9; i++)
                #pragma unroll
                for (int j = 0; j < 9; j++)
                    acc[i][j] = fmaf(qr[i], kr[j], acc[i][j]);
        }

        const float* bp = biasNN + (size_t)(w * HH + h) * NN * NN;
        const float* mp = mask + (size_t)b * NN * NN;
        #pragma unroll
        for (int i = 0; i < 9; i++) {
            const int n = n0 + i;
            #pragma unroll
            for (int j = 0; j < 9; j++) {
                const int m = m0 + j;
                Ss[n * SP + m] = acc[i][j] * SCALE + bp[n * NN + m] + mp[n * NN + m];
            }
        }
    }
    __syncthreads();

    // ---------------- softmax over rows ----------------
    if (tid < NN) {
        float* row = &Ss[tid * SP];
        float mx = row[0];
        for (int m = 1; m < NN; m++) mx = fmaxf(mx, row[m]);
        float sum = 0.f;
        for (int m = 0; m < NN; m++) {
            float e = __expf(row[m] - mx);
            row[m] = e;
            sum += e;
        }
        const float r = 1.f / sum;
        for (int m = 0; m < NN; m++) row[m] *= r;
    }
    __syncthreads();

    // ---------------- Phase C: PV, 8 groups x 18 rows, d = lane ----------------
    {
        float acc[18];
        #pragma unroll
        for (int i = 0; i < 18; i++) acc[i] = 0.f;

        for (int m0 = 0; m0 < NN; m0 += 4) {
            const float vv0 = vs[(m0 + 0) * QP + d];
            const float vv1 = vs[(m0 + 1) * QP + d];
            const float vv2 = vs[(m0 + 2) * QP + d];
            const float vv3 = vs[(m0 + 3) * QP + d];
            #pragma unroll
            for (int i = 0; i < 18; i++) {
                const float4 p = *(const float4*)&Ss[(g * 18 + i) * SP + m0];
                acc[i] = fmaf(p.x, vv0, acc[i]);
                acc[i] = fmaf(p.y, vv1, acc[i]);
                acc[i] = fmaf(p.z, vv2, acc[i]);
                acc[i] = fmaf(p.w, vv3, acc[i]);
            }
        }

        float* op = attn_out + (size_t)(b * NW + w) * NN * CC + h * DH + d;
        #pragma unroll
        for (int i = 0; i < 18; i++)
            op[(size_t)(g * 18 + i) * CC] = acc[i];
    }
}

// ---------------------------------------------------------------------------
// Kernel 3: out = attn_out @ w_proj + b_proj   (138240 x 192 x 192)
// 64 rows per block; A-tile staged in LDS; w_proj through L1 (hot).
// ---------------------------------------------------------------------------
__global__ __launch_bounds__(256) void proj_kernel(
    const float* __restrict__ A, const float* __restrict__ w_proj,
    const float* __restrict__ b_proj, float* __restrict__ out)
{
    __shared__ float As[64 * CC];   // 49,152 B
    const int tid = threadIdx.x;
    const size_t row0 = (size_t)blockIdx.x * 64;

    for (int i = tid; i < 64 * CC; i += 256)
        As[i] = A[row0 * CC + i];
    __syncthreads();

    const int c = tid & 63;   // col within 64-wide tile
    const int g = tid >> 6;   // 4 groups x 16 rows

    for (int ct = 0; ct < 3; ct++) {
        const int col = ct * 64 + c;
        float acc[16];
        const float bp = b_proj[col];
        #pragma unroll
        for (int i = 0; i < 16; i++) acc[i] = bp;

        for (int k0 = 0; k0 < CC; k0 += 16) {
            float wr[16];
            #pragma unroll
            for (int kk = 0; kk < 16; kk++)
                wr[kk] = w_proj[(k0 + kk) * CC + col];
            #pragma unroll
            for (int i = 0; i < 16; i++) {
                const float* ar = &As[(g * 16 + i) * CC + k0];
                #pragma unroll
                for (int kk = 0; kk < 16; kk++)
                    acc[i] = fmaf(ar[kk], wr[kk], acc[i]);
            }
        }
        #pragma unroll
        for (int i = 0; i < 16; i++)
            out[(row0 + g * 16 + i) * CC + col] = acc[i];
    }
}

// ---------------------------------------------------------------------------
extern "C" void kernel_launch(void* const* d_in, const int* in_sizes, int n_in,
                              void* d_out, int out_size, void* d_ws, size_t ws_size,
                              hipStream_t stream)
{
    const float* x          = (const float*)d_in[0];
    const float* mask       = (const float*)d_in[1];
    const float* w_qkv      = (const float*)d_in[2];
    const float* b_qkv      = (const float*)d_in[3];
    const float* w_proj     = (const float*)d_in[4];
    const float* b_proj     = (const float*)d_in[5];
    const float* bias_table = (const float*)d_in[6];
    const int*   pos        = (const int*)d_in[7];
    float* out = (float*)d_out;

    // workspace layout: biasNN [nW,H,N,N] (4.98 MB) | attn_out [B,nW,N,C] (106 MB)
    float* biasNN   = (float*)d_ws;
    float* attn_out = biasNN + (size_t)NW * HH * NN * NN;

    bias_expand_kernel<<<(NW * HH * NN * NN + 255) / 256, 256, 0, stream>>>(
        bias_table, pos, biasNN);
    attn_kernel<<<B_ * NW * HH, 256, 0, stream>>>(
        x, mask, w_qkv, b_qkv, biasNN, attn_out);
    proj_kernel<<<(B_ * NW * NN) / 64, 256, 0, stream>>>(
        attn_out, w_proj, b_proj, out);
}

// Round 2
// 753.505 us; speedup vs baseline: 3.4479x; 3.4479x over previous
//
#include <hip/hip_runtime.h>
#include <math.h>

// EarthAttention3D constants
#define B_   96
#define NW   10
#define NN   144
#define CC   192
#define HH   6
#define DH   32
#define SCALE 0.17677669529663687f  // 1/sqrt(32)

#define XP 200   // x / ao LDS pitch (bf16 elems): 400 B rows -> 2-way bank alias (free)
#define VP 40    // q,k LDS pitch: 80 B rows -> 2-way
#define TP 168   // vT pitch: 336 B rows -> 2-way
#define PP 168   // P (scores) pitch: 336 B rows -> 2-way; cols 144..159 kept zero (K-pad)

typedef __attribute__((ext_vector_type(8))) short v8s;   // 8 x bf16 (4 VGPRs)
typedef __attribute__((ext_vector_type(4))) float v4f;   // MFMA accumulator

__device__ __forceinline__ unsigned short f2b(float f) {  // fp32 -> bf16 RNE
  union { float f; unsigned u; } v; v.f = f;
  unsigned r = v.u + 0x7fffu + ((v.u >> 16) & 1u);
  return (unsigned short)(r >> 16);
}
__device__ __forceinline__ float b2f(unsigned short s) {
  union { unsigned u; float f; } v; v.u = ((unsigned)s) << 16;
  return v.f;
}

// ---------------------------------------------------------------------------
// Prep: wqT[576][192]=w_qkv^T bf16, wpT[192][192]=w_proj^T bf16,
//       biasNN[w][h][n][m] bf16 gathered via position_index.
// ---------------------------------------------------------------------------
#define N_WQT (576*192)
#define N_WPT (192*192)
#define N_BIAS (NW*HH*NN*NN)
__global__ __launch_bounds__(256) void prep_kernel(
    const float* __restrict__ w_qkv, const float* __restrict__ w_proj,
    const float* __restrict__ bias_table, const int* __restrict__ pos,
    unsigned short* __restrict__ wqT, unsigned short* __restrict__ wpT,
    unsigned short* __restrict__ biasNN)
{
  int i = blockIdx.x * 256 + threadIdx.x;
  if (i < N_WQT) {
    int n = i / 192, k = i % 192;
    wqT[i] = f2b(w_qkv[k * 576 + n]);
  } else if (i < N_WQT + N_WPT) {
    int j = i - N_WQT;
    int n = j / 192, k = j % 192;
    wpT[j] = f2b(w_proj[k * 192 + n]);
  } else if (i < N_WQT + N_WPT + N_BIAS) {
    int j = i - (N_WQT + N_WPT);
    int m = j % NN, n = (j / NN) % NN, h = (j / (NN * NN)) % HH, w = j / (NN * NN * HH);
    biasNN[j] = f2b(bias_table[(pos[n * NN + m] * NW + w) * HH + h]);
  }
}

// ---------------------------------------------------------------------------
// Fused QKV + attention per (b,w). 512 threads = 8 waves, ~141 KB LDS.
// MFMA 16x16x32 bf16 everywhere; fp32 softmax (unnormalized exp, divide at end).
// ---------------------------------------------------------------------------
__global__ __launch_bounds__(512, 1) void attn_fused(
    const float* __restrict__ x, const float* __restrict__ mask,
    const float* __restrict__ b_qkv,
    const unsigned short* __restrict__ wqT,
    const unsigned short* __restrict__ biasNN,
    unsigned short* __restrict__ ao)
{
  __shared__ unsigned short xs[NN * XP];   // 57,600 B  x tile bf16
  __shared__ unsigned short qs[NN * VP];   // 11,520 B
  __shared__ unsigned short ks_[NN * VP];  // 11,520 B
  __shared__ unsigned short vT[DH * TP];   // 10,752 B  v transposed [d][m]
  __shared__ unsigned short Ps[NN * PP];   // 48,384 B  logits/probs bf16
  __shared__ float sums[NN];               //     576 B

  const int tid  = threadIdx.x;
  const int wave = tid >> 6;
  const int lane = tid & 63;
  const int lr   = lane & 15;          // fragment row/col index
  const int lk8  = (lane >> 4) * 8;    // fragment k offset
  const int quad = lane >> 4;

  const int bw = blockIdx.x;
  const int b  = bw / NW;
  const int w  = bw % NW;

  // ---- phase 0: stage x (fp32 -> bf16), zero pads ----
  const float4* xp4 = (const float4*)(x + (size_t)bw * NN * CC);
  for (int i = tid; i < NN * CC / 4; i += 512) {
    float4 f = xp4[i];
    int r = i / (CC / 4), c = (i % (CC / 4)) * 4;
    unsigned short* d = &xs[r * XP + c];
    d[0] = f2b(f.x); d[1] = f2b(f.y); d[2] = f2b(f.z); d[3] = f2b(f.w);
  }
  for (int i = tid; i < DH * TP; i += 512) vT[i] = 0;                       // v K-pad
  for (int i = tid; i < NN * 16; i += 512) Ps[(i >> 4) * PP + 144 + (i & 15)] = 0; // P K-pad
  __syncthreads();

  for (int h = 0; h < HH; h++) {
    // ---- phase A: q,k,v = x @ w_qkv[:, head h] + bias.  waves 0..5, 48x48 jobs ----
    if (wave < 6) {
      const int mg = wave >> 1;        // 0..2 : 48-row group
      const int ng = wave & 1;         // 0..1 : 48 of 96 head-cols
      const int r0 = mg * 48;
      v4f acc[3][3];
      #pragma unroll
      for (int jj = 0; jj < 3; jj++) {
        const int nt = ng * 3 + jj;
        const int s = nt >> 1, db = (nt & 1) * 16;
        const float bv = b_qkv[s * CC + h * DH + db + lr];
        #pragma unroll
        for (int ii = 0; ii < 3; ii++) acc[ii][jj] = (v4f){bv, bv, bv, bv};
      }
      #pragma unroll
      for (int ks = 0; ks < 6; ks++) {
        const int k0 = ks * 32;
        v8s a[3];
        #pragma unroll
        for (int ii = 0; ii < 3; ii++)
          a[ii] = *(const v8s*)&xs[(r0 + ii * 16 + lr) * XP + k0 + lk8];
        #pragma unroll
        for (int jj = 0; jj < 3; jj++) {
          const int nt = ng * 3 + jj;
          const int s = nt >> 1, db = (nt & 1) * 16;
          const int nrow = s * CC + h * DH + db + lr;     // row in wqT [576][192]
          v8s bf = *(const v8s*)&wqT[(size_t)nrow * CC + k0 + lk8];
          #pragma unroll
          for (int ii = 0; ii < 3; ii++)
            acc[ii][jj] = __builtin_amdgcn_mfma_f32_16x16x32_bf16(a[ii], bf, acc[ii][jj], 0, 0, 0);
        }
      }
      #pragma unroll
      for (int jj = 0; jj < 3; jj++) {
        const int nt = ng * 3 + jj;
        const int s = nt >> 1, db = (nt & 1) * 16;
        const int dcol = db + lr;
        #pragma unroll
        for (int ii = 0; ii < 3; ii++) {
          #pragma unroll
          for (int r = 0; r < 4; r++) {
            const int row = r0 + ii * 16 + quad * 4 + r;
            const unsigned short val = f2b(acc[ii][jj][r]);
            if (s == 0)      qs[row * VP + dcol]  = val;
            else if (s == 1) ks_[row * VP + dcol] = val;
            else             vT[dcol * TP + row]  = val;   // transposed store
          }
        }
      }
    }
    __syncthreads();

    // ---- phase B: S = scale*q k^T + bias + mask -> bf16 logits in Ps ----
    {
      const unsigned short* bp = biasNN + (size_t)(w * HH + h) * NN * NN;
      const float* mp = mask + (size_t)b * NN * NN;
      for (int t = wave; t < 81; t += 8) {
        const int n0 = (t / 9) * 16;
        const int m0 = (t % 9) * 16;
        v8s aq = *(const v8s*)&qs[(n0 + lr) * VP + lk8];
        v8s bk = *(const v8s*)&ks_[(m0 + lr) * VP + lk8];
        v4f c = {0.f, 0.f, 0.f, 0.f};
        c = __builtin_amdgcn_mfma_f32_16x16x32_bf16(aq, bk, c, 0, 0, 0);
        const int m = m0 + lr;
        #pragma unroll
        for (int r = 0; r < 4; r++) {
          const int n = n0 + quad * 4 + r;
          float v = c[r] * SCALE + b2f(bp[n * NN + m]) + mp[n * NN + m];
          Ps[n * PP + m] = f2b(v);
        }
      }
    }
    __syncthreads();

    // ---- phase C: softmax (one wave per row; store unnormalized exp, keep sums) ----
    for (int rrow = wave; rrow < NN; rrow += 8) {
      unsigned short* prow = &Ps[rrow * PP];
      float v0 = b2f(prow[lane]);
      float v1 = b2f(prow[64 + lane]);
      float v2 = (lane < 16) ? b2f(prow[128 + lane]) : -1e30f;
      float mx = fmaxf(v0, fmaxf(v1, v2));
      #pragma unroll
      for (int off = 32; off > 0; off >>= 1) mx = fmaxf(mx, __shfl_xor(mx, off, 64));
      float e0 = __expf(v0 - mx);
      float e1 = __expf(v1 - mx);
      float e2 = (lane < 16) ? __expf(v2 - mx) : 0.f;
      prow[lane] = f2b(e0);
      prow[64 + lane] = f2b(e1);
      if (lane < 16) prow[128 + lane] = f2b(e2);
      float s = e0 + e1 + e2;
      #pragma unroll
      for (int off = 32; off > 0; off >>= 1) s += __shfl_xor(s, off, 64);
      if (lane == 0) sums[rrow] = s;
    }
    __syncthreads();

    // ---- phase D: O = P @ v (K padded to 160 with zeros), divide by row sum ----
    for (int t = wave; t < 18; t += 8) {
      const int n0 = (t >> 1) * 16;
      const int d0 = (t & 1) * 16;
      v4f c = {0.f, 0.f, 0.f, 0.f};
      #pragma unroll
      for (int ks = 0; ks < 5; ks++) {
        const int k0 = ks * 32;
        v8s ap = *(const v8s*)&Ps[(n0 + lr) * PP + k0 + lk8];
        v8s bv = *(const v8s*)&vT[(d0 + lr) * TP + k0 + lk8];
        c = __builtin_amdgcn_mfma_f32_16x16x32_bf16(ap, bv, c, 0, 0, 0);
      }
      #pragma unroll
      for (int r = 0; r < 4; r++) {
        const int n = n0 + quad * 4 + r;
        const float val = c[r] / sums[n];
        ao[((size_t)bw * NN + n) * CC + h * DH + d0 + lr] = f2b(val);
      }
    }
    __syncthreads();   // protect qs/ks_/vT/Ps before next head overwrites
  }
}

// ---------------------------------------------------------------------------
// Proj: out = ao(bf16) @ w_proj + b_proj, MFMA. 64 rows/block, 6 blocks/CU.
// ---------------------------------------------------------------------------
__global__ __launch_bounds__(256) void proj_mfma(
    const unsigned short* __restrict__ ao,
    const unsigned short* __restrict__ wpT,
    const float* __restrict__ b_proj,
    float* __restrict__ out)
{
  __shared__ unsigned short As[64 * XP];   // 25,600 B
  const int tid  = threadIdx.x;
  const int wave = tid >> 6;
  const int lane = tid & 63;
  const int lr   = lane & 15;
  const int lk8  = (lane >> 4) * 8;
  const int quad = lane >> 4;
  const size_t row0 = (size_t)blockIdx.x * 64;

  for (int i = tid; i < 64 * 24; i += 256) {
    const int r = i / 24, c = i % 24;
    *(v8s*)&As[r * XP + c * 8] = *(const v8s*)(ao + (row0 + r) * CC + c * 8);
  }
  __syncthreads();

  v4f acc[12];
  #pragma unroll
  for (int j = 0; j < 12; j++) {
    const float bv = b_proj[j * 16 + lr];
    acc[j] = (v4f){bv, bv, bv, bv};
  }
  #pragma unroll
  for (int ks = 0; ks < 6; ks++) {
    const int k0 = ks * 32;
    v8s a = *(const v8s*)&As[(wave * 16 + lr) * XP + k0 + lk8];
    #pragma unroll
    for (int j = 0; j < 12; j++) {
      v8s bf = *(const v8s*)(wpT + (j * 16 + lr) * CC + k0 + lk8);
      acc[j] = __builtin_amdgcn_mfma_f32_16x16x32_bf16(a, bf, acc[j], 0, 0, 0);
    }
  }
  #pragma unroll
  for (int j = 0; j < 12; j++) {
    #pragma unroll
    for (int r = 0; r < 4; r++)
      out[(row0 + wave * 16 + quad * 4 + r) * CC + j * 16 + lr] = acc[j][r];
  }
}

// ---------------------------------------------------------------------------
extern "C" void kernel_launch(void* const* d_in, const int* in_sizes, int n_in,
                              void* d_out, int out_size, void* d_ws, size_t ws_size,
                              hipStream_t stream)
{
  const float* x          = (const float*)d_in[0];
  const float* mask       = (const float*)d_in[1];
  const float* w_qkv      = (const float*)d_in[2];
  const float* b_qkv      = (const float*)d_in[3];
  const float* w_proj     = (const float*)d_in[4];
  const float* b_proj     = (const float*)d_in[5];
  const float* bias_table = (const float*)d_in[6];
  const int*   pos        = (const int*)d_in[7];
  float* out = (float*)d_out;

  // ws layout (bf16 elements): biasNN | wqT | wpT | ao
  unsigned short* biasNN = (unsigned short*)d_ws;              // 1,244,160
  unsigned short* wqT    = biasNN + N_BIAS;                    //   110,592
  unsigned short* wpT    = wqT + N_WQT;                        //    36,864
  unsigned short* ao     = wpT + N_WPT;                        // 26,542,080 (~53 MB)

  const int prep_total = N_WQT + N_WPT + N_BIAS;
  prep_kernel<<<(prep_total + 255) / 256, 256, 0, stream>>>(
      w_qkv, w_proj, bias_table, pos, wqT, wpT, biasNN);
  attn_fused<<<B_ * NW, 512, 0, stream>>>(x, mask, b_qkv, wqT, biasNN, ao);
  proj_mfma<<<(B_ * NW * NN) / 64, 256, 0, stream>>>(ao, wpT, b_proj, out);
}

// Round 3
// 747.889 us; speedup vs baseline: 3.4738x; 1.0075x over previous
//
#include <hip/hip_runtime.h>
#include <math.h>

// EarthAttention3D constants
#define B_   96
#define NW   10
#define NN   144
#define CC   192
#define HH   6
#define DH   32
#define SCALE 0.17677669529663687f  // 1/sqrt(32)

#define XP 200   // xs pitch (bf16): 400 B rows
#define PP 168   // Ps pitch: 336 B rows; cols 144..159 zero (K-pad)
#define TP 168   // vT pitch
#define NPASS 3
#define BWCHUNK 320          // 960 / NPASS
#define QKV_STRIDE (NN * DH) // 4608 elems per (h,s) matrix

typedef __attribute__((ext_vector_type(8))) short v8s;   // 8 x bf16
typedef __attribute__((ext_vector_type(4))) float v4f;   // MFMA acc

__device__ __forceinline__ unsigned short f2b(float f) {  // fp32 -> bf16 RNE
  union { float f; unsigned u; } v; v.f = f;
  unsigned r = v.u + 0x7fffu + ((v.u >> 16) & 1u);
  return (unsigned short)(r >> 16);
}
__device__ __forceinline__ float b2f(unsigned short s) {
  union { unsigned u; float f; } v; v.u = ((unsigned)s) << 16;
  return v.f;
}

#define N_WQT (576*192)
#define N_WPT (192*192)
#define N_BIAS (NW*HH*NN*NN)

// ---------------------------------------------------------------------------
// Prep: wqT = w_qkv^T bf16, wpT = w_proj^T bf16, biasNN gathered bf16.
// ---------------------------------------------------------------------------
__global__ __launch_bounds__(256) void prep_kernel(
    const float* __restrict__ w_qkv, const float* __restrict__ w_proj,
    const float* __restrict__ bias_table, const int* __restrict__ pos,
    unsigned short* __restrict__ wqT, unsigned short* __restrict__ wpT,
    unsigned short* __restrict__ biasNN)
{
  int i = blockIdx.x * 256 + threadIdx.x;
  if (i < N_WQT) {
    int n = i / 192, k = i % 192;
    wqT[i] = f2b(w_qkv[k * 576 + n]);
  } else if (i < N_WQT + N_WPT) {
    int j = i - N_WQT;
    int n = j / 192, k = j % 192;
    wpT[j] = f2b(w_proj[k * 192 + n]);
  } else if (i < N_WQT + N_WPT + N_BIAS) {
    int j = i - (N_WQT + N_WPT);
    int m = j % NN, n = (j / NN) % NN, h = (j / (NN * NN)) % HH, w = j / (NN * NN * HH);
    biasNN[j] = f2b(bias_table[(pos[n * NN + m] * NW + w) * HH + h]);
  }
}

// ---------------------------------------------------------------------------
// QKV GEMM: block = (bw, 48-row third). 256 thr / 4 waves, 19.2 KB LDS.
// A-fragments hoisted to registers (reused across all 9 col-strips per wave).
// Output layout: qkv[((bwl*HH + h)*3 + s)][n][d] bf16.
// ---------------------------------------------------------------------------
__global__ __launch_bounds__(256, 3) void qkv_gemm(
    const float* __restrict__ x, const float* __restrict__ b_qkv,
    const unsigned short* __restrict__ wqT,
    unsigned short* __restrict__ qkv, int bw0)
{
  __shared__ unsigned short xs[48 * XP];   // 19,200 B
  const int tid  = threadIdx.x;
  const int wave = tid >> 6, lane = tid & 63;
  const int lr = lane & 15, lk8 = (lane >> 4) * 8, quad = lane >> 4;
  const int bwl = blockIdx.x / 3;
  const int rt3 = blockIdx.x % 3;
  const int bw  = bw0 + bwl;

  // stage 48 rows of x as bf16
  const float4* xp4 = (const float4*)(x + ((size_t)bw * NN + rt3 * 48) * CC);
  for (int i = tid; i < 48 * (CC / 4); i += 256) {
    float4 f = xp4[i];
    int r = i / (CC / 4), c = (i % (CC / 4)) * 4;
    unsigned short* d = &xs[r * XP + c];
    d[0] = f2b(f.x); d[1] = f2b(f.y); d[2] = f2b(f.z); d[3] = f2b(f.w);
  }
  __syncthreads();

  // hoist A-fragments: 3 row-tiles x 6 k-steps = 18 v8s (72 VGPRs)
  v8s a[3][6];
  #pragma unroll
  for (int ii = 0; ii < 3; ii++)
    #pragma unroll
    for (int ks = 0; ks < 6; ks++)
      a[ii][ks] = *(const v8s*)&xs[(ii * 16 + lr) * XP + ks * 32 + lk8];

  for (int c = wave; c < 36; c += 4) {      // 9 col-strips per wave
    const int s = c / 12;
    const int h = (c % 12) >> 1;
    const int dhalf = c & 1;
    const unsigned short* wrow = wqT + (size_t)(c * 16 + lr) * CC;
    v8s bf[6];
    #pragma unroll
    for (int ks = 0; ks < 6; ks++) bf[ks] = *(const v8s*)&wrow[ks * 32 + lk8];
    const float bv = b_qkv[c * 16 + lr];
    v4f acc[3];
    #pragma unroll
    for (int ii = 0; ii < 3; ii++) acc[ii] = (v4f){bv, bv, bv, bv};
    #pragma unroll
    for (int ks = 0; ks < 6; ks++)
      #pragma unroll
      for (int ii = 0; ii < 3; ii++)
        acc[ii] = __builtin_amdgcn_mfma_f32_16x16x32_bf16(a[ii][ks], bf[ks], acc[ii], 0, 0, 0);

    unsigned short* op = qkv + ((size_t)(bwl * HH + h) * 3 + s) * QKV_STRIDE + dhalf * 16 + lr;
    #pragma unroll
    for (int ii = 0; ii < 3; ii++)
      #pragma unroll
      for (int r = 0; r < 4; r++) {
        const int n = rt3 * 48 + ii * 16 + quad * 4 + r;
        op[n * DH] = f2b(acc[ii][r]);
      }
  }
}

// ---------------------------------------------------------------------------
// Attention per (b,w,h): 256 thr / 4 waves, ~60 KB LDS -> 2 blocks/CU.
// q,k read directly from global (L1-hot, 9 KB each). 3 barriers total.
// ---------------------------------------------------------------------------
__global__ __launch_bounds__(256, 2) void attn_bwh(
    const unsigned short* __restrict__ qkv, const float* __restrict__ mask,
    const unsigned short* __restrict__ biasNN,
    unsigned short* __restrict__ ao, int bw0)
{
  __shared__ unsigned short Ps[NN * PP];   // 48,384 B
  __shared__ unsigned short vT[DH * TP];   // 10,752 B
  __shared__ float isum[NN];               //    576 B

  const int tid  = threadIdx.x;
  const int wave = tid >> 6, lane = tid & 63;
  const int lr = lane & 15, lk8 = (lane >> 4) * 8, quad = lane >> 4;

  const int bwl = blockIdx.x / HH;
  const int h   = blockIdx.x % HH;
  const int bw  = bw0 + bwl;
  const int b   = bw / NW;
  const int w   = bw % NW;

  const unsigned short* qp = qkv + (size_t)(bwl * HH + h) * 3 * QKV_STRIDE;
  const unsigned short* kp = qp + QKV_STRIDE;
  const unsigned short* vp = qp + 2 * QKV_STRIDE;

  // init: zero K-pad cols, transpose v into vT
  for (int i = tid; i < DH * 16; i += 256) vT[(i >> 4) * TP + 144 + (i & 15)] = 0;
  for (int i = tid; i < NN * 16; i += 256) Ps[(i >> 4) * PP + 144 + (i & 15)] = 0;
  for (int i = tid; i < NN * DH / 8; i += 256) {
    const int m = i >> 2, d0 = (i & 3) * 8;
    v8s vv = *(const v8s*)&vp[m * DH + d0];
    #pragma unroll
    for (int j = 0; j < 8; j++) vT[(d0 + j) * TP + m] = (unsigned short)vv[j];
  }
  __syncthreads();

  // phase B: S = scale*q k^T + bias + mask -> bf16 logits in Ps
  const unsigned short* bp = biasNN + (size_t)(w * HH + h) * NN * NN;
  const float* mp = mask + (size_t)b * NN * NN;
  for (int mt = wave; mt < 9; mt += 4) {
    v8s bk = *(const v8s*)&kp[(mt * 16 + lr) * DH + lk8];
    const int m = mt * 16 + lr;
    for (int nt = 0; nt < 9; nt++) {
      v8s aq = *(const v8s*)&qp[(nt * 16 + lr) * DH + lk8];
      v4f c = {0.f, 0.f, 0.f, 0.f};
      c = __builtin_amdgcn_mfma_f32_16x16x32_bf16(aq, bk, c, 0, 0, 0);
      #pragma unroll
      for (int r = 0; r < 4; r++) {
        const int n = nt * 16 + quad * 4 + r;
        float v = c[r] * SCALE + b2f(bp[n * NN + m]) + mp[n * NN + m];
        Ps[n * PP + m] = f2b(v);
      }
    }
  }
  __syncthreads();

  // softmax: one wave per row; store unnormalized exp, keep 1/sum
  for (int rrow = wave; rrow < NN; rrow += 4) {
    unsigned short* prow = &Ps[rrow * PP];
    float v0 = b2f(prow[lane]);
    float v1 = b2f(prow[64 + lane]);
    float v2 = (lane < 16) ? b2f(prow[128 + lane]) : -1e30f;
    float mx = fmaxf(v0, fmaxf(v1, v2));
    #pragma unroll
    for (int off = 32; off > 0; off >>= 1) mx = fmaxf(mx, __shfl_xor(mx, off, 64));
    float e0 = __expf(v0 - mx);
    float e1 = __expf(v1 - mx);
    float e2 = (lane < 16) ? __expf(v2 - mx) : 0.f;
    prow[lane] = f2b(e0);
    prow[64 + lane] = f2b(e1);
    if (lane < 16) prow[128 + lane] = f2b(e2);
    float s = e0 + e1 + e2;
    #pragma unroll
    for (int off = 32; off > 0; off >>= 1) s += __shfl_xor(s, off, 64);
    if (lane == 0) isum[rrow] = 1.f / s;
  }
  __syncthreads();

  // phase D: O = P @ v (K padded to 160), scale by 1/sum, write ao
  for (int t = wave; t < 18; t += 4) {
    const int n0 = (t >> 1) * 16;
    const int d0 = (t & 1) * 16;
    v4f c = {0.f, 0.f, 0.f, 0.f};
    #pragma unroll
    for (int ks = 0; ks < 5; ks++) {
      v8s ap = *(const v8s*)&Ps[(n0 + lr) * PP + ks * 32 + lk8];
      v8s bv = *(const v8s*)&vT[(d0 + lr) * TP + ks * 32 + lk8];
      c = __builtin_amdgcn_mfma_f32_16x16x32_bf16(ap, bv, c, 0, 0, 0);
    }
    #pragma unroll
    for (int r = 0; r < 4; r++) {
      const int n = n0 + quad * 4 + r;
      ao[((size_t)bw * NN + n) * CC + h * DH + d0 + lr] = f2b(c[r] * isum[n]);
    }
  }
}

// ---------------------------------------------------------------------------
// Proj: out = ao(bf16) @ w_proj + b_proj. 64 rows/block.
// ---------------------------------------------------------------------------
__global__ __launch_bounds__(256) void proj_mfma(
    const unsigned short* __restrict__ ao,
    const unsigned short* __restrict__ wpT,
    const float* __restrict__ b_proj,
    float* __restrict__ out)
{
  __shared__ unsigned short As[64 * XP];   // 25,600 B
  const int tid  = threadIdx.x;
  const int wave = tid >> 6, lane = tid & 63;
  const int lr = lane & 15, lk8 = (lane >> 4) * 8, quad = lane >> 4;
  const size_t row0 = (size_t)blockIdx.x * 64;

  for (int i = tid; i < 64 * 24; i += 256) {
    const int r = i / 24, c = i % 24;
    *(v8s*)&As[r * XP + c * 8] = *(const v8s*)(ao + (row0 + r) * CC + c * 8);
  }
  __syncthreads();

  v4f acc[12];
  #pragma unroll
  for (int j = 0; j < 12; j++) {
    const float bv = b_proj[j * 16 + lr];
    acc[j] = (v4f){bv, bv, bv, bv};
  }
  #pragma unroll
  for (int ks = 0; ks < 6; ks++) {
    const int k0 = ks * 32;
    v8s a = *(const v8s*)&As[(wave * 16 + lr) * XP + k0 + lk8];
    #pragma unroll
    for (int j = 0; j < 12; j++) {
      v8s bf = *(const v8s*)(wpT + (j * 16 + lr) * CC + k0 + lk8);
      acc[j] = __builtin_amdgcn_mfma_f32_16x16x32_bf16(a, bf, acc[j], 0, 0, 0);
    }
  }
  #pragma unroll
  for (int j = 0; j < 12; j++)
    #pragma unroll
    for (int r = 0; r < 4; r++)
      out[(row0 + wave * 16 + quad * 4 + r) * CC + j * 16 + lr] = acc[j][r];
}

// ---------------------------------------------------------------------------
extern "C" void kernel_launch(void* const* d_in, const int* in_sizes, int n_in,
                              void* d_out, int out_size, void* d_ws, size_t ws_size,
                              hipStream_t stream)
{
  const float* x          = (const float*)d_in[0];
  const float* mask       = (const float*)d_in[1];
  const float* w_qkv      = (const float*)d_in[2];
  const float* b_qkv      = (const float*)d_in[3];
  const float* w_proj     = (const float*)d_in[4];
  const float* b_proj     = (const float*)d_in[5];
  const float* bias_table = (const float*)d_in[6];
  const int*   pos        = (const int*)d_in[7];
  float* out = (float*)d_out;

  // ws layout (bf16 elems): biasNN | wqT | wpT | qkv_chunk | ao  (~109 MB peak)
  unsigned short* biasNN = (unsigned short*)d_ws;                   // 1,244,160
  unsigned short* wqT    = biasNN + N_BIAS;                         //   110,592
  unsigned short* wpT    = wqT + N_WQT;                             //    36,864
  unsigned short* qkvws  = wpT + N_WPT;                             // 26,542,080
  unsigned short* ao     = qkvws + (size_t)BWCHUNK * HH * 3 * QKV_STRIDE; // 26,542,080

  const int prep_total = N_WQT + N_WPT + N_BIAS;
  prep_kernel<<<(prep_total + 255) / 256, 256, 0, stream>>>(
      w_qkv, w_proj, bias_table, pos, wqT, wpT, biasNN);

  for (int p = 0; p < NPASS; p++) {
    const int bw0 = p * BWCHUNK;
    qkv_gemm<<<BWCHUNK * 3, 256, 0, stream>>>(x, b_qkv, wqT, qkvws, bw0);
    attn_bwh<<<BWCHUNK * HH, 256, 0, stream>>>(qkvws, mask, biasNN, ao, bw0);
  }
  proj_mfma<<<(B_ * NW * NN) / 64, 256, 0, stream>>>(ao, wpT, b_proj, out);
}